// Round 4
// baseline (329.329 us; speedup 1.0000x reference)
//
#include <hip/hip_runtime.h>
#include <stdint.h>

#define S_    2048
#define HID_  2048
#define NH_   16
#define NKV_  4
#define HD_   128

using short4x = __attribute__((ext_vector_type(4))) short;
using short8  = __attribute__((ext_vector_type(8))) short;
using floatx4 = __attribute__((ext_vector_type(4))) float;

#define NEGBIG (-3.0e38f)

__device__ __forceinline__ unsigned short f2bf(float x) {
  union { float f; unsigned u; } v; v.f = x;
  unsigned r = v.u + 0x7fffu + ((v.u >> 16) & 1u);
  return (unsigned short)(r >> 16);
}
__device__ __forceinline__ float bf2f(unsigned short b) {
  union { unsigned u; float f; } v; v.u = ((unsigned)b) << 16;
  return v.f;
}
__device__ __forceinline__ void ld_lds16(const void* g, void* l) {
  __builtin_amdgcn_global_load_lds(
      (const __attribute__((address_space(1))) unsigned*)g,
      (__attribute__((address_space(3))) unsigned*)l, 16, 0, 0);
}

// ---------------- fused fp32 -> bf16 convert of all three inputs ----------------
__global__ void k_cvt3(const float* __restrict__ s0, unsigned short* __restrict__ d0, int n0,
                       const float* __restrict__ s1, unsigned short* __restrict__ d1, int n1,
                       const float* __restrict__ s2, unsigned short* __restrict__ d2, int n2) {
  int i = blockIdx.x * blockDim.x + threadIdx.x;
  const float* s; unsigned short* d;
  if (i < n0) { s = s0; d = d0; }
  else if (i < n0 + n1) { s = s1; d = d1; i -= n0; }
  else { s = s2; d = d2; i -= n0 + n1; if (i >= n2) return; }
  float4 v = ((const float4*)s)[i];
  union { unsigned short us[4]; uint2 u2; } u;
  u.us[0] = f2bf(v.x); u.us[1] = f2bf(v.y); u.us[2] = f2bf(v.z); u.us[3] = f2bf(v.w);
  ((uint2*)d)[i] = u.u2;
}

// ------------- fused RoPE (Q then K) in-place, post-scale on Q ----------------
__global__ void k_rope2(unsigned short* __restrict__ Qb, unsigned short* __restrict__ Kb,
                        const int* __restrict__ pos, int nQ, float qscale) {
  int idx = blockIdx.x * blockDim.x + threadIdx.x;
  unsigned short* buf; int nh; float oscale;
  if (idx < nQ) { buf = Qb; nh = NH_; oscale = qscale; }
  else { buf = Kb; nh = NKV_; oscale = 1.0f; idx -= nQ; }
  int d = idx & 63;
  int h = (idx >> 6) % nh;
  int m = idx / (unsigned)(nh << 6);
  float p = (float)pos[m];
  float inv = expf(-(float)d * (13.122363377404328f / 64.0f));
  float f = p * inv;
  float cs = cosf(f), sn = sinf(f);
  size_t base = (size_t)m * (nh * HD_) + h * HD_ + d;
  float x1 = bf2f(buf[base]), x2 = bf2f(buf[base + 64]);
  buf[base]      = f2bf((x1 * cs - x2 * sn) * oscale);
  buf[base + 64] = f2bf((x2 * cs + x1 * sn) * oscale);
}

// ---- bt-GEMM: C[m,n] = sum_k A[m,k]*B[n,k], 128x128 tile, BK=32, async dbuf ----
template <int EPI>
__global__ void __launch_bounds__(256)
k_gemm_bt(const unsigned short* __restrict__ A, const unsigned short* __restrict__ Bw,
          unsigned short* __restrict__ Qb, unsigned short* __restrict__ Kb,
          unsigned short* __restrict__ Vt, float* __restrict__ Of) {
  const int K = HID_;
  __shared__ __align__(16) unsigned short As[2][128 * 32];
  __shared__ __align__(16) unsigned short Bs[2][128 * 32];
  const int tid  = threadIdx.x;
  const int wave = tid >> 6, lane = tid & 63;
  const int quad = lane >> 4, l15 = lane & 15;
  const int wm = (wave >> 1) * 64, wn = (wave & 1) * 64;
  const int m0 = blockIdx.x * 128, n0 = blockIdx.y * 128;

  floatx4 acc[4][4] = {};

  const int srow = tid >> 2;
  const int scol = (tid & 3) * 8;
  const unsigned short* Ag0 = A  + (size_t)(m0 + srow)      * K + scol;
  const unsigned short* Ag1 = A  + (size_t)(m0 + 64 + srow) * K + scol;
  const unsigned short* Bg0 = Bw + (size_t)(n0 + srow)      * K + scol;
  const unsigned short* Bg1 = Bw + (size_t)(n0 + 64 + srow) * K + scol;

  auto stage = [&](int buf, int k0) {
    ld_lds16(Ag0 + k0, &As[buf][tid * 8]);
    ld_lds16(Ag1 + k0, &As[buf][2048 + tid * 8]);
    ld_lds16(Bg0 + k0, &Bs[buf][tid * 8]);
    ld_lds16(Bg1 + k0, &Bs[buf][2048 + tid * 8]);
  };

  stage(0, 0);
  int cur = 0;
  for (int k0 = 0; k0 < K; k0 += 32) {
    __syncthreads();                          // drains stage of buf[cur]
    if (k0 + 32 < K) stage(cur ^ 1, k0 + 32); // in flight during compute
    short8 a[4], b[4];
#pragma unroll
    for (int i = 0; i < 4; i++) a[i] = *(const short8*)&As[cur][(wm + i * 16 + l15) * 32 + quad * 8];
#pragma unroll
    for (int j = 0; j < 4; j++) b[j] = *(const short8*)&Bs[cur][(wn + j * 16 + l15) * 32 + quad * 8];
#pragma unroll
    for (int i = 0; i < 4; i++)
#pragma unroll
      for (int j = 0; j < 4; j++)
        acc[i][j] = __builtin_amdgcn_mfma_f32_16x16x32_bf16(a[i], b[j], acc[i][j], 0, 0, 0);
    cur ^= 1;
  }

#pragma unroll
  for (int i = 0; i < 4; i++) {
#pragma unroll
    for (int j = 0; j < 4; j++) {
      const int col = n0 + wn + j * 16 + l15;
#pragma unroll
      for (int r = 0; r < 4; r++) {
        const int row = m0 + wm + i * 16 + quad * 4 + r;
        float x = acc[i][j][r];
        if (EPI == 0) {
          x = fminf(fmaxf(x, -8.0f), 8.0f);
          if (col < HID_) {
            Qb[(size_t)row * HID_ + col] = f2bf(x);
          } else if (col < HID_ + NKV_ * HD_) {
            Kb[(size_t)row * (NKV_ * HD_) + (col - HID_)] = f2bf(x);
          } else {
            int oo = col - (HID_ + NKV_ * HD_);
            int kvh = oo >> 7, d = oo & 127;
            int bb = row >> 11, ss = row & 2047;
            Vt[((size_t)((bb * NKV_ + kvh) * HD_ + d) << 11) + ss] = f2bf(x);
          }
        } else {
          Of[(size_t)row * HID_ + col] = x;
        }
      }
    }
  }
}

// ------------- flash attention v3: paired q-tiles, S^T MFMA, async dbuf -------
__global__ void __launch_bounds__(256, 2)
k_attn(const unsigned short* __restrict__ Qb, const unsigned short* __restrict__ Kb,
       const unsigned short* __restrict__ Vt, unsigned short* __restrict__ AO) {
  // two staging buffers; per buf: K [4][64][32] @0, V [2][128][32] @8192
  __shared__ __align__(16) unsigned short sm[2][16384];
  __shared__ __align__(16) unsigned short Pl[4][16][80];  // per-wave P, row stride 80

  const int tid  = threadIdx.x;
  const int wave = tid >> 6, lane = tid & 63;
  const int quad = lane >> 4, l15 = lane & 15;
  const int tLow  = blockIdx.x;
  const int tHigh = 31 - tLow;
  const int q0L = tLow * 64, q0H = tHigh * 64;
  const int bh = blockIdx.y;
  const int b = bh >> 4, h = bh & 15;
  const int kvh = h >> 2;

  const int srow = tid >> 2;
  const int scol = (tid & 3) * 8;

  { // stage both Q tiles across buf0+buf1 (dead before first K/V use of buf1)
    const unsigned short* qgL = Qb + (size_t)(b * S_ + q0L + srow) * HID_ + h * HD_ + scol;
    const unsigned short* qgH = Qb + (size_t)(b * S_ + q0H + srow) * HID_ + h * HD_ + scol;
#pragma unroll
    for (int i = 0; i < 4; i++) ld_lds16(qgL + i * 32, &sm[0][i * 2048 + tid * 8]);
#pragma unroll
    for (int i = 0; i < 4; i++) ld_lds16(qgH + i * 32, &sm[1][i * 2048 + tid * 8]);
  }
  __syncthreads();
  short8 qaL[4], qaH[4];
#pragma unroll
  for (int c = 0; c < 4; c++) {
    qaL[c] = *(const short8*)&sm[0][(c * 64 + wave * 16 + l15) * 32 + quad * 8];
    qaH[c] = *(const short8*)&sm[1][(c * 64 + wave * 16 + l15) * 32 + quad * 8];
  }
  __syncthreads();  // all waves done reading Q before buf0 is restaged

  floatx4 oacL[8] = {}, oacH[8] = {};
  floatx4 oacEL = {}, oacEH = {};
  float mL = NEGBIG, mH = NEGBIG;

  const unsigned short* kgb = Kb + (size_t)b * S_ * (NKV_ * HD_) + kvh * HD_ + scol;
  const unsigned short* vgb = Vt + (size_t)(b * NKV_ + kvh) * HD_ * S_;

  unsigned short* PlW = &Pl[wave][0][0];

  short8 ones;
#pragma unroll
  for (int i = 0; i < 8; i++) ones[i] = (short)0x3F80;  // bf16 1.0

  auto stage = [&](int bufI, int j) {
    unsigned short* B = &sm[bufI][0];
    const unsigned short* kg = kgb + (size_t)(j * 64 + srow) * (NKV_ * HD_);
#pragma unroll
    for (int i = 0; i < 4; i++) ld_lds16(kg + i * 32, &B[i * 2048 + tid * 8]);
#pragma unroll
    for (int i = 0; i < 4; i++) {
      int c = i >> 1, rowd = (i & 1) * 64 + srow;
      ld_lds16(vgb + (size_t)rowd * S_ + j * 64 + c * 32 + scol,
               &B[8192 + c * 4096 + (i & 1) * 2048 + tid * 8]);
    }
  };

  auto attn_step = [&](const short8* qa, floatx4* oac, floatx4& oacE, float& m_run,
                       int q0, int j, bool diag, const unsigned short* Kt,
                       const unsigned short* Vts) {
    floatx4 sc[4] = {};
#pragma unroll
    for (int t = 0; t < 4; t++)
#pragma unroll
      for (int c = 0; c < 4; c++) {
        short8 ka = *(const short8*)&Kt[c * 2048 + (t * 16 + l15) * 32 + quad * 8];
        sc[t] = __builtin_amdgcn_mfma_f32_16x16x32_bf16(ka, qa[c], sc[t], 0, 0, 0);
      }

    if (diag) {
      const int rowq = q0 + wave * 16 + l15;
#pragma unroll
      for (int t = 0; t < 4; t++) {
        const int kb0 = j * 64 + t * 16 + quad * 4;
#pragma unroll
        for (int r = 0; r < 4; r++)
          if (kb0 + r > rowq) sc[t][r] = NEGBIG;
      }
    }

    float mx = sc[0][0];
#pragma unroll
    for (int t = 0; t < 4; t++)
#pragma unroll
      for (int r = 0; r < 4; r++) mx = fmaxf(mx, sc[t][r]);
    mx = fmaxf(mx, __shfl_xor(mx, 16));
    mx = fmaxf(mx, __shfl_xor(mx, 32));

    const float mo = m_run;
    m_run = fmaxf(mo, mx);
    if (__any(mx > mo)) {
      float alpha = __builtin_amdgcn_exp2f(mo - m_run);
      float al4[4];
#pragma unroll
      for (int r = 0; r < 4; r++) al4[r] = __shfl(alpha, quad * 4 + r, 16);
#pragma unroll
      for (int t = 0; t < 8; t++)
#pragma unroll
        for (int r = 0; r < 4; r++) oac[t][r] *= al4[r];
#pragma unroll
      for (int r = 0; r < 4; r++) oacE[r] *= al4[r];
    }

#pragma unroll
    for (int t = 0; t < 4; t++) {
      short4x pk;
#pragma unroll
      for (int r = 0; r < 4; r++)
        pk[r] = (short)f2bf(__builtin_amdgcn_exp2f(sc[t][r] - m_run));
      *(short4x*)&PlW[l15 * 80 + t * 16 + quad * 4] = pk;
    }

    short8 pa0 = *(const short8*)&PlW[l15 * 80 + quad * 8];
    short8 pa1 = *(const short8*)&PlW[l15 * 80 + 32 + quad * 8];
#pragma unroll
    for (int t = 0; t < 8; t++) {
      short8 vb0 = *(const short8*)&Vts[(t * 16 + l15) * 32 + quad * 8];
      oac[t] = __builtin_amdgcn_mfma_f32_16x16x32_bf16(pa0, vb0, oac[t], 0, 0, 0);
      short8 vb1 = *(const short8*)&Vts[4096 + (t * 16 + l15) * 32 + quad * 8];
      oac[t] = __builtin_amdgcn_mfma_f32_16x16x32_bf16(pa1, vb1, oac[t], 0, 0, 0);
    }
    oacE = __builtin_amdgcn_mfma_f32_16x16x32_bf16(pa0, ones, oacE, 0, 0, 0);
    oacE = __builtin_amdgcn_mfma_f32_16x16x32_bf16(pa1, ones, oacE, 0, 0, 0);
  };

  stage(0, 0);
  int cur = 0;
  for (int j = 0; j <= tHigh; ++j) {
    __syncthreads();
    if (j < tHigh) stage(cur ^ 1, j + 1);
    const unsigned short* Kt  = &sm[cur][0];
    const unsigned short* Vts = Kt + 8192;
    attn_step(qaH, oacH, oacEH, mH, q0H, j, j == tHigh, Kt, Vts);
    if (j <= tLow) attn_step(qaL, oacL, oacEL, mL, q0L, j, j == tLow, Kt, Vts);
    cur ^= 1;
  }

#pragma unroll
  for (int t = 0; t < 8; t++)
#pragma unroll
    for (int r = 0; r < 4; r++) {
      int rgL = q0L + wave * 16 + quad * 4 + r;
      int rgH = q0H + wave * 16 + quad * 4 + r;
      AO[(size_t)(b * S_ + rgL) * HID_ + h * HD_ + t * 16 + l15] = f2bf(oacL[t][r] / oacEL[r]);
      AO[(size_t)(b * S_ + rgH) * HID_ + h * HD_ + t * 16 + l15] = f2bf(oacH[t][r] / oacEH[r]);
    }
}

extern "C" void kernel_launch(void* const* d_in, const int* in_sizes, int n_in,
                              void* d_out, int out_size, void* d_ws, size_t ws_size,
                              hipStream_t stream) {
  (void)in_sizes; (void)n_in; (void)out_size; (void)ws_size;
  const float* hidden = (const float*)d_in[0];
  const int*   pos    = (const int*)d_in[1];
  const float* Wqkv   = (const float*)d_in[2];
  const float* Wout   = (const float*)d_in[3];
  float* out = (float*)d_out;

  unsigned short* ws = (unsigned short*)d_ws;
  const size_t M1 = 1024 * 1024;
  unsigned short* hb  = ws;
  unsigned short* wqb = ws + 8 * M1;
  unsigned short* wob = ws + 14 * M1;
  unsigned short* Qb  = ws + 18 * M1;
  unsigned short* Kb  = ws + 26 * M1;
  unsigned short* Vt  = ws + 28 * M1;
  unsigned short* AO  = hb;

  const float QSCL = 0.08838834764831845f * 1.4426950408889634f;
  const int nQrope = 2 * 2048 * NH_ * 64;   // 4194304
  const int nKrope = 2 * 2048 * NKV_ * 64;  // 1048576

  k_cvt3<<<18432, 256, 0, stream>>>(hidden, hb, 2097152,
                                    Wqkv, wqb, 1572864,
                                    Wout, wob, 1048576);
  k_gemm_bt<0><<<dim3(32, 24), 256, 0, stream>>>(hb, wqb, Qb, Kb, Vt, nullptr);
  k_rope2<<<(nQrope + nKrope) / 256, 256, 0, stream>>>(Qb, Kb, pos, nQrope, QSCL);
  k_attn<<<dim3(16, 32), 256, 0, stream>>>(Qb, Kb, Vt, AO);
  k_gemm_bt<1><<<dim3(32, 16), 256, 0, stream>>>(AO, wob, nullptr, nullptr, nullptr, out);
}

// Round 5
// 319.615 us; speedup vs baseline: 1.0304x; 1.0304x over previous
//
#include <hip/hip_runtime.h>
#include <stdint.h>

#define S_    2048
#define HID_  2048
#define NH_   16
#define NKV_  4
#define HD_   128

using short4x = __attribute__((ext_vector_type(4))) short;
using short8  = __attribute__((ext_vector_type(8))) short;
using floatx4 = __attribute__((ext_vector_type(4))) float;

#define NEGBIG (-3.0e38f)

__device__ __forceinline__ unsigned short f2bf(float x) {
  union { float f; unsigned u; } v; v.f = x;
  unsigned r = v.u + 0x7fffu + ((v.u >> 16) & 1u);
  return (unsigned short)(r >> 16);
}
__device__ __forceinline__ float bf2f(unsigned short b) {
  union { unsigned u; float f; } v; v.u = ((unsigned)b) << 16;
  return v.f;
}
__device__ __forceinline__ void ld_lds16(const void* g, void* l) {
  __builtin_amdgcn_global_load_lds(
      (const __attribute__((address_space(1))) unsigned*)g,
      (__attribute__((address_space(3))) unsigned*)l, 16, 0, 0);
}

// ---------------- fused fp32 -> bf16 convert of all three inputs ----------------
__global__ void k_cvt3(const float* __restrict__ s0, unsigned short* __restrict__ d0, int n0,
                       const float* __restrict__ s1, unsigned short* __restrict__ d1, int n1,
                       const float* __restrict__ s2, unsigned short* __restrict__ d2, int n2) {
  int i = blockIdx.x * blockDim.x + threadIdx.x;
  const float* s; unsigned short* d;
  if (i < n0) { s = s0; d = d0; }
  else if (i < n0 + n1) { s = s1; d = d1; i -= n0; }
  else { s = s2; d = d2; i -= n0 + n1; if (i >= n2) return; }
  float4 v = ((const float4*)s)[i];
  union { unsigned short us[4]; uint2 u2; } u;
  u.us[0] = f2bf(v.x); u.us[1] = f2bf(v.y); u.us[2] = f2bf(v.z); u.us[3] = f2bf(v.w);
  ((uint2*)d)[i] = u.u2;
}

// ------------- fused RoPE (Q then K) in-place, post-scale on Q ----------------
__global__ void k_rope2(unsigned short* __restrict__ Qb, unsigned short* __restrict__ Kb,
                        const int* __restrict__ pos, int nQ, float qscale) {
  int idx = blockIdx.x * blockDim.x + threadIdx.x;
  unsigned short* buf; int nh; float oscale;
  if (idx < nQ) { buf = Qb; nh = NH_; oscale = qscale; }
  else { buf = Kb; nh = NKV_; oscale = 1.0f; idx -= nQ; }
  int d = idx & 63;
  int h = (idx >> 6) % nh;
  int m = idx / (unsigned)(nh << 6);
  float p = (float)pos[m];
  float inv = expf(-(float)d * (13.122363377404328f / 64.0f));
  float f = p * inv;
  float cs = cosf(f), sn = sinf(f);
  size_t base = (size_t)m * (nh * HD_) + h * HD_ + d;
  float x1 = bf2f(buf[base]), x2 = bf2f(buf[base + 64]);
  buf[base]      = f2bf((x1 * cs - x2 * sn) * oscale);
  buf[base + 64] = f2bf((x2 * cs + x1 * sn) * oscale);
}

// ---- bt-GEMM: C[m,n] = sum_k A[m,k]*B[n,k], 128x128 tile, BK=32 (m97 single-buf)
template <int EPI>
__global__ void __launch_bounds__(256)
k_gemm_bt(const unsigned short* __restrict__ A, const unsigned short* __restrict__ Bw,
          unsigned short* __restrict__ Qb, unsigned short* __restrict__ Kb,
          unsigned short* __restrict__ Vt, float* __restrict__ Of) {
  const int K = HID_;
  __shared__ __align__(16) unsigned short As[128 * 32];
  __shared__ __align__(16) unsigned short Bs[128 * 32];
  const int tid  = threadIdx.x;
  const int wave = tid >> 6, lane = tid & 63;
  const int quad = lane >> 4, l15 = lane & 15;
  const int wm = (wave >> 1) * 64, wn = (wave & 1) * 64;
  const int m0 = blockIdx.x * 128, n0 = blockIdx.y * 128;

  floatx4 acc[4][4] = {};

  const int srow = tid >> 2;
  const int scol = (tid & 3) * 8;
  const unsigned short* Ag0 = A  + (size_t)(m0 + srow)      * K + scol;
  const unsigned short* Ag1 = A  + (size_t)(m0 + 64 + srow) * K + scol;
  const unsigned short* Bg0 = Bw + (size_t)(n0 + srow)      * K + scol;
  const unsigned short* Bg1 = Bw + (size_t)(n0 + 64 + srow) * K + scol;
  unsigned short* lA0 = &As[tid * 8];
  unsigned short* lA1 = &As[2048 + tid * 8];
  unsigned short* lB0 = &Bs[tid * 8];
  unsigned short* lB1 = &Bs[2048 + tid * 8];

  for (int k0 = 0; k0 < K; k0 += 32) {
    __syncthreads();
    ld_lds16(Ag0 + k0, lA0);
    ld_lds16(Ag1 + k0, lA1);
    ld_lds16(Bg0 + k0, lB0);
    ld_lds16(Bg1 + k0, lB1);
    __syncthreads();
    short8 a[4], b[4];
#pragma unroll
    for (int i = 0; i < 4; i++) a[i] = *(const short8*)&As[(wm + i * 16 + l15) * 32 + quad * 8];
#pragma unroll
    for (int j = 0; j < 4; j++) b[j] = *(const short8*)&Bs[(wn + j * 16 + l15) * 32 + quad * 8];
#pragma unroll
    for (int i = 0; i < 4; i++)
#pragma unroll
      for (int j = 0; j < 4; j++)
        acc[i][j] = __builtin_amdgcn_mfma_f32_16x16x32_bf16(a[i], b[j], acc[i][j], 0, 0, 0);
  }

#pragma unroll
  for (int i = 0; i < 4; i++) {
#pragma unroll
    for (int j = 0; j < 4; j++) {
      const int col = n0 + wn + j * 16 + l15;
#pragma unroll
      for (int r = 0; r < 4; r++) {
        const int row = m0 + wm + i * 16 + quad * 4 + r;
        float x = acc[i][j][r];
        if (EPI == 0) {
          x = fminf(fmaxf(x, -8.0f), 8.0f);
          if (col < HID_) {
            Qb[(size_t)row * HID_ + col] = f2bf(x);
          } else if (col < HID_ + NKV_ * HD_) {
            Kb[(size_t)row * (NKV_ * HD_) + (col - HID_)] = f2bf(x);
          } else {
            int oo = col - (HID_ + NKV_ * HD_);
            int kvh = oo >> 7, d = oo & 127;
            int bb = row >> 11, ss = row & 2047;
            Vt[((size_t)((bb * NKV_ + kvh) * HD_ + d) << 11) + ss] = f2bf(x);
          }
        } else {
          Of[(size_t)row * HID_ + col] = x;
        }
      }
    }
  }
}

// --- flash attention v4: paired q-tiles with SHARED K/V fragment reads --------
__global__ void __launch_bounds__(256, 2)
k_attn(const unsigned short* __restrict__ Qb, const unsigned short* __restrict__ Kb,
       const unsigned short* __restrict__ Vt, unsigned short* __restrict__ AO) {
  // two staging buffers; per buf: K [4][64][32] @0, V [2][128][32] @8192
  __shared__ __align__(16) unsigned short sm[2][16384];
  __shared__ __align__(16) unsigned short Pl[4][16][80];  // per-wave P, row stride 80

  const int tid  = threadIdx.x;
  const int wave = tid >> 6, lane = tid & 63;
  const int quad = lane >> 4, l15 = lane & 15;
  const int tLow  = blockIdx.x;
  const int tHigh = 31 - tLow;
  const int q0L = tLow * 64, q0H = tHigh * 64;
  const int bh = blockIdx.y;
  const int b = bh >> 4, h = bh & 15;
  const int kvh = h >> 2;

  const int srow = tid >> 2;
  const int scol = (tid & 3) * 8;

  { // stage both Q tiles across buf0+buf1 (dead before first K/V use of buf1)
    const unsigned short* qgL = Qb + (size_t)(b * S_ + q0L + srow) * HID_ + h * HD_ + scol;
    const unsigned short* qgH = Qb + (size_t)(b * S_ + q0H + srow) * HID_ + h * HD_ + scol;
#pragma unroll
    for (int i = 0; i < 4; i++) ld_lds16(qgL + i * 32, &sm[0][i * 2048 + tid * 8]);
#pragma unroll
    for (int i = 0; i < 4; i++) ld_lds16(qgH + i * 32, &sm[1][i * 2048 + tid * 8]);
  }
  __syncthreads();
  short8 qaL[4], qaH[4];
#pragma unroll
  for (int c = 0; c < 4; c++) {
    qaL[c] = *(const short8*)&sm[0][(c * 64 + wave * 16 + l15) * 32 + quad * 8];
    qaH[c] = *(const short8*)&sm[1][(c * 64 + wave * 16 + l15) * 32 + quad * 8];
  }
  __syncthreads();  // all waves done reading Q before buf0 is restaged

  floatx4 oacL[8] = {}, oacH[8] = {};
  floatx4 oacEL = {}, oacEH = {};
  float mL = NEGBIG, mH = NEGBIG;

  const unsigned short* kgb = Kb + (size_t)b * S_ * (NKV_ * HD_) + kvh * HD_ + scol;
  const unsigned short* vgb = Vt + (size_t)(b * NKV_ + kvh) * HD_ * S_;

  unsigned short* PlW = &Pl[wave][0][0];

  short8 ones;
#pragma unroll
  for (int i = 0; i < 8; i++) ones[i] = (short)0x3F80;  // bf16 1.0

  auto stage = [&](int bufI, int j) {
    unsigned short* B = &sm[bufI][0];
    const unsigned short* kg = kgb + (size_t)(j * 64 + srow) * (NKV_ * HD_);
#pragma unroll
    for (int i = 0; i < 4; i++) ld_lds16(kg + i * 32, &B[i * 2048 + tid * 8]);
#pragma unroll
    for (int i = 0; i < 4; i++) {
      int c = i >> 1, rowd = (i & 1) * 64 + srow;
      ld_lds16(vgb + (size_t)rowd * S_ + j * 64 + c * 32 + scol,
               &B[8192 + c * 4096 + (i & 1) * 2048 + tid * 8]);
    }
  };

  // softmax on one tile's scores: mask, running max, rescale, P->LDS, P->regs
  auto softmax_tile = [&](floatx4* sc, floatx4* oac, floatx4& oacE, float& m_run,
                          int q0, int j, bool diag, short8& pa0, short8& pa1) {
    if (diag) {
      const int rowq = q0 + wave * 16 + l15;
#pragma unroll
      for (int t = 0; t < 4; t++) {
        const int kb0 = j * 64 + t * 16 + quad * 4;
#pragma unroll
        for (int r = 0; r < 4; r++)
          if (kb0 + r > rowq) sc[t][r] = NEGBIG;
      }
    }
    float mx = sc[0][0];
#pragma unroll
    for (int t = 0; t < 4; t++)
#pragma unroll
      for (int r = 0; r < 4; r++) mx = fmaxf(mx, sc[t][r]);
    mx = fmaxf(mx, __shfl_xor(mx, 16));
    mx = fmaxf(mx, __shfl_xor(mx, 32));

    const float mo = m_run;
    m_run = fmaxf(mo, mx);
    if (__any(mx > mo)) {
      float alpha = __builtin_amdgcn_exp2f(mo - m_run);
      float al4[4];
#pragma unroll
      for (int r = 0; r < 4; r++) al4[r] = __shfl(alpha, quad * 4 + r, 16);
#pragma unroll
      for (int t = 0; t < 8; t++)
#pragma unroll
        for (int r = 0; r < 4; r++) oac[t][r] *= al4[r];
#pragma unroll
      for (int r = 0; r < 4; r++) oacE[r] *= al4[r];
    }
#pragma unroll
    for (int t = 0; t < 4; t++) {
      short4x pk;
#pragma unroll
      for (int r = 0; r < 4; r++)
        pk[r] = (short)f2bf(__builtin_amdgcn_exp2f(sc[t][r] - m_run));
      *(short4x*)&PlW[l15 * 80 + t * 16 + quad * 4] = pk;
    }
    pa0 = *(const short8*)&PlW[l15 * 80 + quad * 8];
    pa1 = *(const short8*)&PlW[l15 * 80 + 32 + quad * 8];
  };

  // fused step: both tiles share every K/V fragment read
  auto step_two = [&](int j, const unsigned short* Kt, const unsigned short* Vts,
                      bool diagL, bool diagH) {
    floatx4 scH[4] = {}, scL[4] = {};
#pragma unroll
    for (int t = 0; t < 4; t++)
#pragma unroll
      for (int c = 0; c < 4; c++) {
        short8 ka = *(const short8*)&Kt[c * 2048 + (t * 16 + l15) * 32 + quad * 8];
        scH[t] = __builtin_amdgcn_mfma_f32_16x16x32_bf16(ka, qaH[c], scH[t], 0, 0, 0);
        scL[t] = __builtin_amdgcn_mfma_f32_16x16x32_bf16(ka, qaL[c], scL[t], 0, 0, 0);
      }
    short8 paH0, paH1, paL0, paL1;
    softmax_tile(scH, oacH, oacEH, mH, q0H, j, diagH, paH0, paH1);
    softmax_tile(scL, oacL, oacEL, mL, q0L, j, diagL, paL0, paL1);
#pragma unroll
    for (int t = 0; t < 8; t++) {
      short8 vb0 = *(const short8*)&Vts[(t * 16 + l15) * 32 + quad * 8];
      oacH[t] = __builtin_amdgcn_mfma_f32_16x16x32_bf16(paH0, vb0, oacH[t], 0, 0, 0);
      oacL[t] = __builtin_amdgcn_mfma_f32_16x16x32_bf16(paL0, vb0, oacL[t], 0, 0, 0);
      short8 vb1 = *(const short8*)&Vts[4096 + (t * 16 + l15) * 32 + quad * 8];
      oacH[t] = __builtin_amdgcn_mfma_f32_16x16x32_bf16(paH1, vb1, oacH[t], 0, 0, 0);
      oacL[t] = __builtin_amdgcn_mfma_f32_16x16x32_bf16(paL1, vb1, oacL[t], 0, 0, 0);
    }
    oacEH = __builtin_amdgcn_mfma_f32_16x16x32_bf16(paH0, ones, oacEH, 0, 0, 0);
    oacEH = __builtin_amdgcn_mfma_f32_16x16x32_bf16(paH1, ones, oacEH, 0, 0, 0);
    oacEL = __builtin_amdgcn_mfma_f32_16x16x32_bf16(paL0, ones, oacEL, 0, 0, 0);
    oacEL = __builtin_amdgcn_mfma_f32_16x16x32_bf16(paL1, ones, oacEL, 0, 0, 0);
  };

  // single-tile step (H only), for j > tLow
  auto step_one = [&](int j, const unsigned short* Kt, const unsigned short* Vts, bool diagH) {
    floatx4 scH[4] = {};
#pragma unroll
    for (int t = 0; t < 4; t++)
#pragma unroll
      for (int c = 0; c < 4; c++) {
        short8 ka = *(const short8*)&Kt[c * 2048 + (t * 16 + l15) * 32 + quad * 8];
        scH[t] = __builtin_amdgcn_mfma_f32_16x16x32_bf16(ka, qaH[c], scH[t], 0, 0, 0);
      }
    short8 paH0, paH1;
    softmax_tile(scH, oacH, oacEH, mH, q0H, j, diagH, paH0, paH1);
#pragma unroll
    for (int t = 0; t < 8; t++) {
      short8 vb0 = *(const short8*)&Vts[(t * 16 + l15) * 32 + quad * 8];
      oacH[t] = __builtin_amdgcn_mfma_f32_16x16x32_bf16(paH0, vb0, oacH[t], 0, 0, 0);
      short8 vb1 = *(const short8*)&Vts[4096 + (t * 16 + l15) * 32 + quad * 8];
      oacH[t] = __builtin_amdgcn_mfma_f32_16x16x32_bf16(paH1, vb1, oacH[t], 0, 0, 0);
    }
    oacEH = __builtin_amdgcn_mfma_f32_16x16x32_bf16(paH0, ones, oacEH, 0, 0, 0);
    oacEH = __builtin_amdgcn_mfma_f32_16x16x32_bf16(paH1, ones, oacEH, 0, 0, 0);
  };

  stage(0, 0);
  int cur = 0;
  for (int j = 0; j <= tHigh; ++j) {
    __syncthreads();
    if (j < tHigh) stage(cur ^ 1, j + 1);
    const unsigned short* Kt  = &sm[cur][0];
    const unsigned short* Vts = Kt + 8192;
    if (j <= tLow) step_two(j, Kt, Vts, j == tLow, j == tHigh);
    else           step_one(j, Kt, Vts, j == tHigh);
    cur ^= 1;
  }

#pragma unroll
  for (int t = 0; t < 8; t++)
#pragma unroll
    for (int r = 0; r < 4; r++) {
      int rgL = q0L + wave * 16 + quad * 4 + r;
      int rgH = q0H + wave * 16 + quad * 4 + r;
      AO[(size_t)(b * S_ + rgL) * HID_ + h * HD_ + t * 16 + l15] = f2bf(oacL[t][r] / oacEL[r]);
      AO[(size_t)(b * S_ + rgH) * HID_ + h * HD_ + t * 16 + l15] = f2bf(oacH[t][r] / oacEH[r]);
    }
}

extern "C" void kernel_launch(void* const* d_in, const int* in_sizes, int n_in,
                              void* d_out, int out_size, void* d_ws, size_t ws_size,
                              hipStream_t stream) {
  (void)in_sizes; (void)n_in; (void)out_size; (void)ws_size;
  const float* hidden = (const float*)d_in[0];
  const int*   pos    = (const int*)d_in[1];
  const float* Wqkv   = (const float*)d_in[2];
  const float* Wout   = (const float*)d_in[3];
  float* out = (float*)d_out;

  unsigned short* ws = (unsigned short*)d_ws;
  const size_t M1 = 1024 * 1024;
  unsigned short* hb  = ws;
  unsigned short* wqb = ws + 8 * M1;
  unsigned short* wob = ws + 14 * M1;
  unsigned short* Qb  = ws + 18 * M1;
  unsigned short* Kb  = ws + 26 * M1;
  unsigned short* Vt  = ws + 28 * M1;
  unsigned short* AO  = hb;

  const float QSCL = 0.08838834764831845f * 1.4426950408889634f;
  const int nQrope = 2 * 2048 * NH_ * 64;   // 4194304
  const int nKrope = 2 * 2048 * NKV_ * 64;  // 1048576

  k_cvt3<<<18432, 256, 0, stream>>>(hidden, hb, 2097152,
                                    Wqkv, wqb, 1572864,
                                    Wout, wob, 1048576);
  k_gemm_bt<0><<<dim3(32, 24), 256, 0, stream>>>(hb, wqb, Qb, Kb, Vt, nullptr);
  k_rope2<<<(nQrope + nKrope) / 256, 256, 0, stream>>>(Qb, Kb, pos, nQrope, QSCL);
  k_attn<<<dim3(16, 32), 256, 0, stream>>>(Qb, Kb, Vt, AO);
  k_gemm_bt<1><<<dim3(32, 16), 256, 0, stream>>>(AO, wob, nullptr, nullptr, nullptr, out);
}